// Round 14
// baseline (30.385 us; speedup 1.0000x reference)
//
#include <hip/hip_runtime.h>

#define HW  (1024u*1024u)
#define CHW (2u*HW)
#define MAXP 65536u
#define LABEL_OFF 1048576u
#define SCORE_OFF 1572864u
#define NINF (-3.0e38f)

__device__ __forceinline__ float max3f(float a, float b, float c) {
    return fmaxf(fmaxf(a, b), c);
}

// ---- A: 7x7 NMS mask + per-WAVE in-order pair emission ----
// 1024 blocks, XCD-swizzled; block = one 16-row stripe of one image = one chunk.
// Wave wv = col segment [256wv, 256wv+256); emits to its own 128-pair sub-buffer
// in (row, lane) order; per-(pair-iter) packed counts let scatter rebuild
// the global ascending-flat order. ONE barrier per pair-iteration (rowbuf only).
__global__ __launch_bounds__(256, 4) void mask_kernel(const float* __restrict__ map,
                                                      uint2* __restrict__ pairs,
                                                      unsigned* __restrict__ counts,
                                                      unsigned* __restrict__ chunkCount) {
    __shared__ float4 rowbuf[2][2][258];       // [parity][rowInPair][col4+pads]
    __shared__ unsigned sred[4];
    int bid0 = blockIdx.x;
    int bid = (bid0 & 7) * 128 + (bid0 >> 3);  // XCD swizzle (bijective: 1024 % 8 == 0)
    int tid = threadIdx.x;
    int stripe = bid & 63;
    int img = bid >> 6;                        // b*2 + c
    int r0 = stripe << 4;
    int lane = tid & 63, wv = tid >> 6;
    const float4* __restrict__ base = (const float4*)(map + ((size_t)img << 20));
    const size_t pbase = (size_t)bid * 512u + (size_t)wv * 128u;

    if (tid < 8) {                             // NINF pads at [*][*][0] and [*][*][257]
        float4 n4 = make_float4(NINF, NINF, NINF, NINF);
        rowbuf[(tid >> 2) & 1][(tid >> 1) & 1][(tid & 1) * 257] = n4;
    }

    // column-validity nibble (cols 6..1017 valid)
    int c0 = tid * 4;
    int cvm = 0;
    #pragma unroll
    for (int j = 0; j < 4; ++j) {
        int cc = c0 + j;
        if (cc >= 6 && cc <= 1017) cvm |= (1 << j);
    }

    // rolling 12-slot window: input row q -> slot (q - r0 + 3) mod 12
    float4 w[12];
    #pragma unroll
    for (int k = 0; k < 10; ++k) {             // rows r0-3 .. r0+6
        int rr = r0 - 3 + k;
        w[k] = ((unsigned)rr < 1024u) ? base[rr * 256 + tid]
                                      : make_float4(NINF, NINF, NINF, NINF);
    }

    unsigned woff = 0;                         // this wave's pairs emitted so far

    #pragma unroll
    for (int p = 0; p < 8; ++p) {              // pair rows rA = r0+2p, rB = rA+1
        int rA = r0 + 2 * p;
        if (p < 6) {                           // prefetch rows rA+7, rA+8 (for iter p+2)
            int q1 = rA + 7, q2 = rA + 8;
            w[(2 * p + 10) % 12] = ((unsigned)q1 < 1024u) ? base[q1 * 256 + tid]
                                                          : make_float4(NINF, NINF, NINF, NINF);
            w[(2 * p + 11) % 12] = ((unsigned)q2 < 1024u) ? base[q2 * 256 + tid]
                                                          : make_float4(NINF, NINF, NINF, NINF);
        }
        float4 s0 = w[(2 * p + 0) % 12], s1 = w[(2 * p + 1) % 12];
        float4 s2 = w[(2 * p + 2) % 12], s3 = w[(2 * p + 3) % 12];
        float4 s4 = w[(2 * p + 4) % 12], s5 = w[(2 * p + 5) % 12];
        float4 s6 = w[(2 * p + 6) % 12], s7 = w[(2 * p + 7) % 12];

        // vertical: common6 = max(rows rA-2..rA+3); vmA = max(c6, rA-3); vmB = max(c6, rA+4)
        float4 c6, vmA, vmB;
        c6.x = fmaxf(max3f(s1.x, s2.x, s3.x), max3f(s4.x, s5.x, s6.x));
        c6.y = fmaxf(max3f(s1.y, s2.y, s3.y), max3f(s4.y, s5.y, s6.y));
        c6.z = fmaxf(max3f(s1.z, s2.z, s3.z), max3f(s4.z, s5.z, s6.z));
        c6.w = fmaxf(max3f(s1.w, s2.w, s3.w), max3f(s4.w, s5.w, s6.w));
        vmA.x = fmaxf(c6.x, s0.x); vmB.x = fmaxf(c6.x, s7.x);
        vmA.y = fmaxf(c6.y, s0.y); vmB.y = fmaxf(c6.y, s7.y);
        vmA.z = fmaxf(c6.z, s0.z); vmB.z = fmaxf(c6.z, s7.z);
        vmA.w = fmaxf(c6.w, s0.w); vmB.w = fmaxf(c6.w, s7.w);

        rowbuf[p & 1][0][tid + 1] = vmA;
        rowbuf[p & 1][1][tid + 1] = vmB;
        __syncthreads();
        float4 LA = rowbuf[p & 1][0][tid], RA = rowbuf[p & 1][0][tid + 2];
        float4 LB = rowbuf[p & 1][1][tid], RB = rowbuf[p & 1][1][tid + 2];

        // horizontal 7-max
        float mA0 = max3f(max3f(LA.y, LA.z, LA.w),  max3f(vmA.x, vmA.y, vmA.z), vmA.w);
        float mA1 = max3f(max3f(LA.z, LA.w, vmA.x), max3f(vmA.y, vmA.z, vmA.w), RA.x);
        float mA2 = max3f(max3f(LA.w, vmA.x, vmA.y), max3f(vmA.z, vmA.w, RA.x), RA.y);
        float mA3 = max3f(max3f(vmA.x, vmA.y, vmA.z), max3f(vmA.w, RA.x, RA.y), RA.z);
        float mB0 = max3f(max3f(LB.y, LB.z, LB.w),  max3f(vmB.x, vmB.y, vmB.z), vmB.w);
        float mB1 = max3f(max3f(LB.z, LB.w, vmB.x), max3f(vmB.y, vmB.z, vmB.w), RB.x);
        float mB2 = max3f(max3f(LB.w, vmB.x, vmB.y), max3f(vmB.z, vmB.w, RB.x), RB.y);
        float mB3 = max3f(max3f(vmB.x, vmB.y, vmB.z), max3f(vmB.w, RB.x, RB.y), RB.z);

        float4 ctrA = s3, ctrB = s4;            // original rows rA, rB
        int fA0 = (ctrA.x == mA0) & (ctrA.x > 0.5f);
        int fA1 = (ctrA.y == mA1) & (ctrA.y > 0.5f);
        int fA2 = (ctrA.z == mA2) & (ctrA.z > 0.5f);
        int fA3 = (ctrA.w == mA3) & (ctrA.w > 0.5f);
        int fB0 = (ctrB.x == mB0) & (ctrB.x > 0.5f);
        int fB1 = (ctrB.y == mB1) & (ctrB.y > 0.5f);
        int fB2 = (ctrB.z == mB2) & (ctrB.z > 0.5f);
        int fB3 = (ctrB.w == mB3) & (ctrB.w > 0.5f);
        int nibA = (fA0 | (fA1 << 1) | (fA2 << 2) | (fA3 << 3)) & cvm;
        int nibB = (fB0 | (fB1 << 1) | (fB2 << 2) | (fB3 << 3)) & cvm;
        int rowokA = (rA >= 6) & (rA <= 1017);
        int rowokB = ((rA + 1) >= 6) & ((rA + 1) <= 1017);
        nibA = rowokA ? nibA : 0;
        nibB = rowokB ? nibB : 0;

        // ---- wave-local packed scan (no cross-wave, no extra barrier) ----
        unsigned packed = (unsigned)__popc((unsigned)nibA)
                        | ((unsigned)__popc((unsigned)nibB) << 16);
        unsigned incl = packed;
        #pragma unroll
        for (int off = 1; off < 64; off <<= 1) {
            unsigned nn = __shfl_up(incl, off, 64);
            if (lane >= off) incl += nn;
        }
        if (lane == 63) counts[bid * 32 + wv * 8 + p] = incl;   // packed (sumA|sumB<<16)
        unsigned tot = __shfl(incl, 63, 64);
        unsigned excl = incl - packed;
        unsigned sumA = tot & 0xFFFFu;
        unsigned posA = woff + (excl & 0xFFFFu);
        unsigned posB = woff + sumA + (excl >> 16);
        woff += sumA + (tot >> 16);

        unsigned flatbase = ((unsigned)(img & 1) << 20) | ((unsigned)rA << 10)
                          | ((unsigned)tid * 4u);
        if (nibA & 1) { if (posA < 128u) pairs[pbase + posA] = make_uint2(flatbase + 0u, __float_as_uint(ctrA.x)); posA++; }
        if (nibA & 2) { if (posA < 128u) pairs[pbase + posA] = make_uint2(flatbase + 1u, __float_as_uint(ctrA.y)); posA++; }
        if (nibA & 4) { if (posA < 128u) pairs[pbase + posA] = make_uint2(flatbase + 2u, __float_as_uint(ctrA.z)); posA++; }
        if (nibA & 8) { if (posA < 128u) pairs[pbase + posA] = make_uint2(flatbase + 3u, __float_as_uint(ctrA.w)); posA++; }
        if (nibB & 1) { if (posB < 128u) pairs[pbase + posB] = make_uint2(flatbase + 1024u, __float_as_uint(ctrB.x)); posB++; }
        if (nibB & 2) { if (posB < 128u) pairs[pbase + posB] = make_uint2(flatbase + 1025u, __float_as_uint(ctrB.y)); posB++; }
        if (nibB & 4) { if (posB < 128u) pairs[pbase + posB] = make_uint2(flatbase + 1026u, __float_as_uint(ctrB.z)); posB++; }
        if (nibB & 8) { if (posB < 128u) pairs[pbase + posB] = make_uint2(flatbase + 1027u, __float_as_uint(ctrB.w)); posB++; }
    }

    // per-chunk total (woff is wave-uniform)
    if (lane == 0) sred[wv] = woff;
    __syncthreads();
    if (tid == 0) chunkCount[bid] = sred[0] + sred[1] + sred[2] + sred[3];
}

// ---- B: order-reconstructing coalesced scatter + tail pad (512 threads) ----
__global__ __launch_bounds__(512) void scan_scatter(const uint2* __restrict__ pairs,
                                                    const unsigned* __restrict__ counts,
                                                    const unsigned* __restrict__ chunkCount,
                                                    float* __restrict__ out) {
    int bid0 = blockIdx.x;
    int blk = (bid0 & 7) * 128 + (bid0 >> 3);   // match mask's chunk->XCD mapping
    int b = blk >> 7, cib = blk & 127;
    int tid = threadIdx.x;
    int lane = tid & 63, wv = tid >> 6;         // wv 0..7

    __shared__ unsigned long long sw[8];
    __shared__ unsigned sbase, stotal;
    __shared__ unsigned short cnt16[16][4];     // [row][seg]
    __shared__ unsigned short dstS[64];         // excl prefix, (row,seg) order
    __shared__ unsigned short segS[64];         // excl prefix, (seg,row) order

    // decode per-(row,seg) counts (32 packed u32 -> 64 u16)
    if (tid < 32) {
        unsigned cv = counts[blk * 32 + tid];   // seg = tid>>3, p = tid&7
        int seg = tid >> 3, p = tid & 7;
        cnt16[2 * p][seg]     = (unsigned short)(cv & 0xFFFFu);
        cnt16[2 * p + 1][seg] = (unsigned short)(cv >> 16);
    }

    // packed reduce: low32 = sum over chunks < cib (base), high32 = sum over all (total)
    unsigned cc = (tid < 128) ? chunkCount[b * 128 + tid] : 0u;
    unsigned long long v = ((tid < cib) ? (unsigned long long)cc : 0ull)
                         | ((unsigned long long)cc << 32);
    for (int off = 32; off; off >>= 1) v += __shfl_down(v, off, 64);
    if (lane == 0) sw[wv] = v;
    __syncthreads();                            // cnt16 + sw visible
    if (tid == 0) {
        unsigned long long t = sw[0] + sw[1] + sw[2] + sw[3] + sw[4] + sw[5] + sw[6] + sw[7];
        sbase  = (unsigned)t;
        stotal = (unsigned)(t >> 32);
    }

    // wave 0: (row,seg)-order exclusive prefix -> dstS
    // wave 1: (seg,row)-order exclusive prefix -> segS
    if (wv == 0) {
        unsigned val = cnt16[lane >> 2][lane & 3];
        unsigned incl = val;
        #pragma unroll
        for (int off = 1; off < 64; off <<= 1) {
            unsigned nn = __shfl_up(incl, off, 64);
            if (lane >= off) incl += nn;
        }
        dstS[lane] = (unsigned short)(incl - val);
    } else if (wv == 1) {
        unsigned val = cnt16[lane & 15][lane >> 4];
        unsigned incl = val;
        #pragma unroll
        for (int off = 1; off < 64; off <<= 1) {
            unsigned nn = __shfl_up(incl, off, 64);
            if (lane >= off) incl += nn;
        }
        segS[lane] = (unsigned short)(incl - val);
    }
    __syncthreads();                            // dstS/segS/sbase/stotal visible

    // copy: thread t owns sub-buffer slot (seg = t>>7, idx = t&127)
    int seg = tid >> 7, idx = tid & 127;
    unsigned segBase = segS[seg * 16];          // pairs before this seg's stream
    unsigned segTot  = (unsigned)segS[seg * 16 + 15] + (unsigned)cnt16[15][seg] - segBase;
    if ((unsigned)idx < segTot) {
        uint2 pr = pairs[(size_t)blk * 512u + (size_t)seg * 128u + idx];
        unsigned flat = pr.x;
        unsigned row = (flat >> 10) & 15u;      // row within 16-row chunk
        unsigned slot = sbase + (unsigned)dstS[row * 4 + seg]
                      + (unsigned)idx - ((unsigned)segS[seg * 16 + row] - segBase);
        if (slot < MAXP) {
            unsigned c = flat >> 20;
            unsigned h = (flat >> 10) & 1023u;
            unsigned wcol = flat & 1023u;
            unsigned o = b * MAXP + slot;
            out[2u * o]         = (float)wcol;           // x
            out[2u * o + 1]     = (float)h;              // y
            out[LABEL_OFF + o]  = (float)(c + 1u);       // label
            out[SCORE_OFF + o]  = __uint_as_float(pr.y); // score
        }
    }

    // tail padding: one slot per thread in this chunk's 512-slot slice
    unsigned slot = ((unsigned)cib) * 512u + (unsigned)tid;
    if (slot >= stotal) {                        // slot < 65536 by construction
        unsigned o = b * MAXP + slot;
        float2 neg1; neg1.x = -1.0f; neg1.y = -1.0f;
        ((float2*)out)[o]   = neg1;              // coords (x,y) = -1
        out[LABEL_OFF + o]  = 0.0f;
        out[SCORE_OFF + o]  = 0.0f;
    }
}

extern "C" void kernel_launch(void* const* d_in, const int* in_sizes, int n_in,
                              void* d_out, int out_size, void* d_ws, size_t ws_size,
                              hipStream_t stream) {
    const float* map = (const float*)d_in[0];
    float* out = (float*)d_out;
    uint2* pairs = (uint2*)d_ws;                                 // 1024*512*8B = 4 MB
    unsigned* counts = (unsigned*)((char*)d_ws + 4194304);       // 1024*32 u32 = 128 KB
    unsigned* chunkCount = (unsigned*)((char*)d_ws + 4325376);   // 1024 u32

    mask_kernel<<<1024, 256, 0, stream>>>(map, pairs, counts, chunkCount);
    scan_scatter<<<1024, 512, 0, stream>>>(pairs, counts, chunkCount, out);
}